// Round 1
// baseline (506.442 us; speedup 1.0000x reference)
//
#include <hip/hip_runtime.h>
#include <hip/hip_bf16.h>
#include <stdint.h>

#define N 8192
#define D 128

typedef __bf16 bf16x8_t __attribute__((ext_vector_type(8)));
typedef __bf16 bf16x2_t __attribute__((ext_vector_type(2)));
typedef float  f32x4_t  __attribute__((ext_vector_type(4)));

// --- Kernel 1: row-normalize embeddings, cast to bf16 into workspace -------
// One wave (64 lanes) per row, 2 floats/lane, shuffle reduction over 64 lanes.
__global__ __launch_bounds__(256) void normalize_k(const float* __restrict__ emb,
                                                   __bf16* __restrict__ xb) {
    const int row  = blockIdx.x * 4 + (threadIdx.x >> 6);
    const int lane = threadIdx.x & 63;
    const float2* src = reinterpret_cast<const float2*>(emb + (size_t)row * D);
    float2 v = src[lane];
    float ss = v.x * v.x + v.y * v.y;
#pragma unroll
    for (int off = 32; off; off >>= 1) ss += __shfl_xor(ss, off);
    const float inv = 1.0f / fmaxf(sqrtf(ss), 1e-8f);
    bf16x2_t o;
    o.x = (__bf16)(v.x * inv);
    o.y = (__bf16)(v.y * inv);
    *reinterpret_cast<bf16x2_t*>(xb + (size_t)row * D + lane * 2) = o;
}

// --- Kernel 2: fused X*X^T tile + (pred - sim)^2 partial sum ---------------
// Block = 256 threads (4 waves). Output tile 128x128: wave w covers rows
// [w*32, w*32+32) x all 128 cols as a 2x8 grid of 16x16 MFMA tiles. K=128 in
// 4 steps of 32. Both operands are row-major x_bf16 (A.B^T pattern): lane
// loads 8 contiguous bf16 (16B) from row (tile + lane&15), k-offset (lane>>4)*8.
// x_bf16 is 2MB -> lives in L2; sim is the 256MB HBM stream, read once.
__global__ __launch_bounds__(256) void gemm_loss_k(const __bf16* __restrict__ xb,
                                                   const float* __restrict__ sim,
                                                   float* __restrict__ acc_out) {
    const int lane = threadIdx.x & 63;
    const int wave = threadIdx.x >> 6;
    const int m = lane & 15;   // fragment row (A) / col (B); also C col
    const int q = lane >> 4;   // k-quad; also C row-quad
    const int i_base = blockIdx.y * 128 + wave * 32;
    const int j_base = blockIdx.x * 128;

    const f32x4_t zero = {0.0f, 0.0f, 0.0f, 0.0f};
    f32x4_t acc[2][8];
#pragma unroll
    for (int t = 0; t < 2; ++t)
#pragma unroll
        for (int s = 0; s < 8; ++s) acc[t][s] = zero;

#pragma unroll
    for (int kk = 0; kk < 4; ++kk) {
        const int kofs = kk * 32 + q * 8;
        bf16x8_t a[2], b[8];
#pragma unroll
        for (int t = 0; t < 2; ++t)
            a[t] = *reinterpret_cast<const bf16x8_t*>(
                xb + (size_t)(i_base + t * 16 + m) * D + kofs);
#pragma unroll
        for (int s = 0; s < 8; ++s)
            b[s] = *reinterpret_cast<const bf16x8_t*>(
                xb + (size_t)(j_base + s * 16 + m) * D + kofs);
#pragma unroll
        for (int t = 0; t < 2; ++t)
#pragma unroll
            for (int s = 0; s < 8; ++s)
                acc[t][s] = __builtin_amdgcn_mfma_f32_16x16x32_bf16(
                    a[t], b[s], acc[t][s], 0, 0, 0);
    }

    // C/D layout (verified m89/m91): col = lane&15, row = (lane>>4)*4 + reg.
    // sim reads: 16 consecutive floats per quad = full 64B cachelines.
    float local = 0.0f;
#pragma unroll
    for (int t = 0; t < 2; ++t) {
#pragma unroll
        for (int s = 0; s < 8; ++s) {
            const int col = j_base + s * 16 + m;
#pragma unroll
            for (int r = 0; r < 4; ++r) {
                const int row = i_base + t * 16 + q * 4 + r;
                const float d = acc[t][s][r] - sim[(size_t)row * N + col];
                local = fmaf(d, d, local);
            }
        }
    }
#pragma unroll
    for (int off = 32; off; off >>= 1) local += __shfl_xor(local, off);
    __shared__ float wsum[4];
    if (lane == 0) wsum[wave] = local;
    __syncthreads();
    if (threadIdx.x == 0)
        atomicAdd(acc_out, wsum[0] + wsum[1] + wsum[2] + wsum[3]);
}

// --- Kernel 3: finalize -----------------------------------------------------
__global__ void finalize_k(const float* __restrict__ acc, float* __restrict__ out) {
    out[0] = acc[0] * (1.0f / ((float)N * (float)N));
}

extern "C" void kernel_launch(void* const* d_in, const int* in_sizes, int n_in,
                              void* d_out, int out_size, void* d_ws, size_t ws_size,
                              hipStream_t stream) {
    const float* emb = (const float*)d_in[0];
    const float* sim = (const float*)d_in[1];
    __bf16* xb = (__bf16*)d_ws;                                   // 2 MB bf16 x
    float* acc = (float*)((char*)d_ws + (size_t)N * D * sizeof(__bf16));

    hipMemsetAsync(acc, 0, sizeof(float), stream);
    normalize_k<<<N / 4, 256, 0, stream>>>(emb, xb);
    gemm_loss_k<<<dim3(N / 128, N / 128), 256, 0, stream>>>(xb, sim, acc);
    finalize_k<<<1, 1, 0, stream>>>(acc, (float*)d_out);
}

// Round 2
// 425.497 us; speedup vs baseline: 1.1902x; 1.1902x over previous
//
#include <hip/hip_runtime.h>
#include <hip/hip_bf16.h>
#include <stdint.h>

#define N 8192
#define D 128

typedef __bf16 bf16x8_t __attribute__((ext_vector_type(8)));
typedef __bf16 bf16x2_t __attribute__((ext_vector_type(2)));
typedef float  f32x4_t  __attribute__((ext_vector_type(4)));

// --- Kernel 1: row-normalize embeddings, cast to bf16 into workspace -------
__global__ __launch_bounds__(256) void normalize_k(const float* __restrict__ emb,
                                                   __bf16* __restrict__ xb) {
    const int row  = blockIdx.x * 4 + (threadIdx.x >> 6);
    const int lane = threadIdx.x & 63;
    const float2* src = reinterpret_cast<const float2*>(emb + (size_t)row * D);
    float2 v = src[lane];
    float ss = v.x * v.x + v.y * v.y;
#pragma unroll
    for (int off = 32; off; off >>= 1) ss += __shfl_xor(ss, off);
    const float inv = 1.0f / fmaxf(sqrtf(ss), 1e-8f);
    bf16x2_t o;
    o.x = (__bf16)(v.x * inv);
    o.y = (__bf16)(v.y * inv);
    *reinterpret_cast<bf16x2_t*>(xb + (size_t)row * D + lane * 2) = o;
}

// --- Kernel 2: fused X*X^T tile + (pred - sim)^2 partial sum ---------------
// 128 rows x 64 cols per block (256 thr, 4 waves; wave = 32 rows x 64 cols =
// 2x4 grid of 16x16 MFMA tiles). Sim values (32/thread) are PREFETCHED into
// VGPRs before the MFMA loop so the ~900-cycle HBM latency overlaps compute.
// Nontemporal: sim is a read-once 256MB stream; keep xb (2MB) L2-resident.
__global__ __launch_bounds__(256) void gemm_loss_k(const __bf16* __restrict__ xb,
                                                   const float* __restrict__ sim,
                                                   float* __restrict__ acc_out) {
    const int lane = threadIdx.x & 63;
    const int wave = threadIdx.x >> 6;
    const int m = lane & 15;   // fragment row (A) / col (B); also C col
    const int q = lane >> 4;   // k-quad; also C row-quad
    const int i_base = blockIdx.y * 128 + wave * 32;
    const int j_base = blockIdx.x * 64;

    // ---- Prefetch sim tile values (MFMA C-layout addresses) ----
    float sv[2][4][4];
#pragma unroll
    for (int t = 0; t < 2; ++t)
#pragma unroll
        for (int s = 0; s < 4; ++s)
#pragma unroll
            for (int r = 0; r < 4; ++r)
                sv[t][s][r] = __builtin_nontemporal_load(
                    sim + (size_t)(i_base + t * 16 + q * 4 + r) * N
                        + (j_base + s * 16 + m));

    // ---- MFMA: K=128 in 4 steps of 32 ----
    const f32x4_t zero = {0.0f, 0.0f, 0.0f, 0.0f};
    f32x4_t acc[2][4];
#pragma unroll
    for (int t = 0; t < 2; ++t)
#pragma unroll
        for (int s = 0; s < 4; ++s) acc[t][s] = zero;

#pragma unroll
    for (int kk = 0; kk < 4; ++kk) {
        const int kofs = kk * 32 + q * 8;
        bf16x8_t a[2], b[4];
#pragma unroll
        for (int t = 0; t < 2; ++t)
            a[t] = *reinterpret_cast<const bf16x8_t*>(
                xb + (size_t)(i_base + t * 16 + m) * D + kofs);
#pragma unroll
        for (int s = 0; s < 4; ++s)
            b[s] = *reinterpret_cast<const bf16x8_t*>(
                xb + (size_t)(j_base + s * 16 + m) * D + kofs);
#pragma unroll
        for (int t = 0; t < 2; ++t)
#pragma unroll
            for (int s = 0; s < 4; ++s)
                acc[t][s] = __builtin_amdgcn_mfma_f32_16x16x32_bf16(
                    a[t], b[s], acc[t][s], 0, 0, 0);
    }

    // ---- Epilogue: (pred - sim)^2 with prefetched sim ----
    float local = 0.0f;
#pragma unroll
    for (int t = 0; t < 2; ++t)
#pragma unroll
        for (int s = 0; s < 4; ++s)
#pragma unroll
            for (int r = 0; r < 4; ++r) {
                const float d = acc[t][s][r] - sv[t][s][r];
                local = fmaf(d, d, local);
            }
#pragma unroll
    for (int off = 32; off; off >>= 1) local += __shfl_xor(local, off);
    __shared__ float wsum[4];
    if (lane == 0) wsum[wave] = local;
    __syncthreads();
    if (threadIdx.x == 0)
        atomicAdd(acc_out, wsum[0] + wsum[1] + wsum[2] + wsum[3]);
}

// --- Kernel 3: finalize -----------------------------------------------------
__global__ void finalize_k(const float* __restrict__ acc, float* __restrict__ out) {
    out[0] = acc[0] * (1.0f / ((float)N * (float)N));
}

extern "C" void kernel_launch(void* const* d_in, const int* in_sizes, int n_in,
                              void* d_out, int out_size, void* d_ws, size_t ws_size,
                              hipStream_t stream) {
    const float* emb = (const float*)d_in[0];
    const float* sim = (const float*)d_in[1];
    __bf16* xb = (__bf16*)d_ws;                                   // 2 MB bf16 x
    float* acc = (float*)((char*)d_ws + (size_t)N * D * sizeof(__bf16));

    hipMemsetAsync(acc, 0, sizeof(float), stream);
    normalize_k<<<N / 4, 256, 0, stream>>>(emb, xb);
    gemm_loss_k<<<dim3(N / 64, N / 128), 256, 0, stream>>>(xb, sim, acc);
    finalize_k<<<1, 1, 0, stream>>>(acc, (float*)d_out);
}

// Round 3
// 418.960 us; speedup vs baseline: 1.2088x; 1.0156x over previous
//
#include <hip/hip_runtime.h>
#include <hip/hip_bf16.h>
#include <stdint.h>

#define N 8192
#define D 128
#define NBLOCKS ((N / 64) * (N / 128))   // 8192 partial sums

typedef __bf16 bf16x8_t __attribute__((ext_vector_type(8)));
typedef __bf16 bf16x2_t __attribute__((ext_vector_type(2)));
typedef float  f32x4_t  __attribute__((ext_vector_type(4)));

// --- Kernel 1: row-normalize embeddings, cast to bf16 into workspace -------
__global__ __launch_bounds__(256) void normalize_k(const float* __restrict__ emb,
                                                   __bf16* __restrict__ xb) {
    const int row  = blockIdx.x * 4 + (threadIdx.x >> 6);
    const int lane = threadIdx.x & 63;
    const float2* src = reinterpret_cast<const float2*>(emb + (size_t)row * D);
    float2 v = src[lane];
    float ss = v.x * v.x + v.y * v.y;
#pragma unroll
    for (int off = 32; off; off >>= 1) ss += __shfl_xor(ss, off);
    const float inv = 1.0f / fmaxf(sqrtf(ss), 1e-8f);
    bf16x2_t o;
    o.x = (__bf16)(v.x * inv);
    o.y = (__bf16)(v.y * inv);
    *reinterpret_cast<bf16x2_t*>(xb + (size_t)row * D + lane * 2) = o;
}

// --- Kernel 2: fused X*X^T tile + (pred - sim)^2 partial sum ---------------
// 128 rows x 64 cols per block. ORDERING MATTERS: xb fragment loads issue
// FIRST, sim loads SECOND -> MFMA's s_waitcnt (in-order vmcnt) only drains
// the older xb loads; the 32 sim loads stay in flight under the MFMAs.
// NO global atomic: partial sum -> private slot in d_ws (contention-free).
__global__ __launch_bounds__(256) void gemm_loss_k(const __bf16* __restrict__ xb,
                                                   const float* __restrict__ sim,
                                                   float* __restrict__ partials) {
    const int lane = threadIdx.x & 63;
    const int wave = threadIdx.x >> 6;
    const int m = lane & 15;   // fragment row (A) / col (B); also C col
    const int q = lane >> 4;   // k-quad; also C row-quad
    const int i_base = blockIdx.y * 128 + wave * 32;
    const int j_base = blockIdx.x * 64;

    // ---- xb fragment loads (issued first; MFMA waits only on these) ----
    bf16x8_t a[4][2], b[4][4];
#pragma unroll
    for (int kk = 0; kk < 4; ++kk) {
        const int kofs = kk * 32 + q * 8;
#pragma unroll
        for (int t = 0; t < 2; ++t)
            a[kk][t] = *reinterpret_cast<const bf16x8_t*>(
                xb + (size_t)(i_base + t * 16 + m) * D + kofs);
#pragma unroll
        for (int s = 0; s < 4; ++s)
            b[kk][s] = *reinterpret_cast<const bf16x8_t*>(
                xb + (size_t)(j_base + s * 16 + m) * D + kofs);
    }

    // ---- sim prefetch (issued second; completes under MFMA) ----
    float sv[2][4][4];
#pragma unroll
    for (int t = 0; t < 2; ++t)
#pragma unroll
        for (int s = 0; s < 4; ++s)
#pragma unroll
            for (int r = 0; r < 4; ++r)
                sv[t][s][r] = __builtin_nontemporal_load(
                    sim + (size_t)(i_base + t * 16 + q * 4 + r) * N
                        + (j_base + s * 16 + m));

    // ---- MFMA: K=128 in 4 steps of 32 ----
    const f32x4_t zero = {0.0f, 0.0f, 0.0f, 0.0f};
    f32x4_t acc[2][4];
#pragma unroll
    for (int t = 0; t < 2; ++t)
#pragma unroll
        for (int s = 0; s < 4; ++s) acc[t][s] = zero;
#pragma unroll
    for (int kk = 0; kk < 4; ++kk)
#pragma unroll
        for (int t = 0; t < 2; ++t)
#pragma unroll
            for (int s = 0; s < 4; ++s)
                acc[t][s] = __builtin_amdgcn_mfma_f32_16x16x32_bf16(
                    a[kk][t], b[kk][s], acc[t][s], 0, 0, 0);

    // ---- Epilogue: (pred - sim)^2, wave + block reduce, private slot ----
    float local = 0.0f;
#pragma unroll
    for (int t = 0; t < 2; ++t)
#pragma unroll
        for (int s = 0; s < 4; ++s)
#pragma unroll
            for (int r = 0; r < 4; ++r) {
                const float d = acc[t][s][r] - sv[t][s][r];
                local = fmaf(d, d, local);
            }
#pragma unroll
    for (int off = 32; off; off >>= 1) local += __shfl_xor(local, off);
    __shared__ float wsum[4];
    if (lane == 0) wsum[wave] = local;
    __syncthreads();
    if (threadIdx.x == 0) {
        const int bid = blockIdx.y * gridDim.x + blockIdx.x;
        partials[bid] = wsum[0] + wsum[1] + wsum[2] + wsum[3];
    }
}

// --- Kernel 3: reduce 8192 partials, finalize ------------------------------
__global__ __launch_bounds__(256) void finalize_k(const float* __restrict__ partials,
                                                  float* __restrict__ out) {
    float s = 0.0f;
#pragma unroll
    for (int i = 0; i < NBLOCKS / 256; ++i)
        s += partials[i * 256 + threadIdx.x];
#pragma unroll
    for (int off = 32; off; off >>= 1) s += __shfl_xor(s, off);
    __shared__ float wsum[4];
    if ((threadIdx.x & 63) == 0) wsum[threadIdx.x >> 6] = s;
    __syncthreads();
    if (threadIdx.x == 0)
        out[0] = (wsum[0] + wsum[1] + wsum[2] + wsum[3])
                 * (1.0f / ((float)N * (float)N));
}

extern "C" void kernel_launch(void* const* d_in, const int* in_sizes, int n_in,
                              void* d_out, int out_size, void* d_ws, size_t ws_size,
                              hipStream_t stream) {
    const float* emb = (const float*)d_in[0];
    const float* sim = (const float*)d_in[1];
    __bf16* xb = (__bf16*)d_ws;                                   // 2 MB bf16 x
    float* partials = (float*)((char*)d_ws + (size_t)N * D * sizeof(__bf16));

    normalize_k<<<N / 4, 256, 0, stream>>>(emb, xb);
    gemm_loss_k<<<dim3(N / 64, N / 128), 256, 0, stream>>>(xb, sim, partials);
    finalize_k<<<1, 256, 0, stream>>>(partials, (float*)d_out);
}